// Round 21
// baseline (49.901 us; speedup 1.0000x reference)
//
#include <hip/hip_runtime.h>
#include <hip/hip_bf16.h>
#include <hip/hip_fp8.h>
#include <math.h>

typedef __attribute__((ext_vector_type(4))) float f32x4;

#define NB 8192
#define ND 256
#define NBT 2080          // 64*65/2 triangle tiles at 128x128
#define LN2f 0.6931471805599453f

__device__ __forceinline__ float bf2f(ushort u) {
  unsigned int x = ((unsigned int)u) << 16;
  return __builtin_bit_cast(float, x);
}
__device__ __forceinline__ ushort f2bf(float x) {
  return __builtin_bit_cast(ushort, __float2bfloat16(x));
}

// ---- prep: normalize, fold 1/sqrt(T*ln2), quantize to fp8 e4m3;          ----
// ---- write hs (bf16 of dequant, exact) + hsK8 (fp8 K-major) + dbuf      ----
// hsK8 layout: [tile128][ku 0..31][row 0..127] of 8B units
__global__ void prep_kernel(const float* __restrict__ h, ushort* __restrict__ hs,
                            unsigned char* __restrict__ hsK8,
                            float* __restrict__ dbuf) {
  const float SCALE = 1.0f / sqrtf(0.07f * LN2f);
  int lane = threadIdx.x & 63, wave = threadIdx.x >> 6;
  int r = blockIdx.x * 4 + wave;
  float4 v = reinterpret_cast<const float4*>(h + (size_t)r * ND)[lane];
  float ss = v.x * v.x + v.y * v.y + v.z * v.z + v.w * v.w;
#pragma unroll
  for (int d = 1; d <= 32; d <<= 1) ss += __shfl_xor(ss, d);
  float scale = SCALE / fmaxf(sqrtf(ss), 1e-12f);
  __hip_fp8_e4m3 q0(v.x * scale), q1(v.y * scale), q2(v.z * scale), q3(v.w * scale);
  uchar4 qb;
  qb.x = q0.__x; qb.y = q1.__x; qb.z = q2.__x; qb.w = q3.__x;
  float qx = (float)q0, qy = (float)q1, qz = (float)q2, qw = (float)q3;
  ushort4 o;
  o.x = f2bf(qx); o.y = f2bf(qy); o.z = f2bf(qz); o.w = f2bf(qw);  // exact
  reinterpret_cast<ushort4*>(hs + (size_t)r * ND)[lane] = o;
  *reinterpret_cast<uchar4*>(hsK8 + (size_t)(r >> 7) * 32768 +
                             (size_t)(lane >> 1) * 1024 + (size_t)(r & 127) * 8 +
                             (lane & 1) * 4) = qb;
  float dd = qx * qx + qy * qy + qz * qz + qw * qw;
#pragma unroll
  for (int d = 1; d <= 32; d <<= 1) dd += __shfl_xor(dd, d);
  if (lane == 0) dbuf[r] = dd;
}

// stage one 32KB fp8 panel (contiguous) into LDS: pure linear copy
__device__ __forceinline__ void stage32k(unsigned char* lds,
                                         const unsigned char* __restrict__ g,
                                         int tid) {
#pragma unroll
  for (int i = 0; i < 8; ++i) {
    int u = i * 256 + tid;            // 16B unit, 0..2047
    __builtin_amdgcn_global_load_lds(
        (const __attribute__((address_space(1))) unsigned int*)(g + (size_t)u * 16),
        (__attribute__((address_space(3))) unsigned int*)(lds + (size_t)u * 16),
        16, 0, 0);
  }
}

// ---- main: 100 classsum blocks first, then 2080 single-stage LDS fp8 tiles --
__global__ __launch_bounds__(256)
void main_kernel(const unsigned char* __restrict__ hsK8,
                 const ushort* __restrict__ hs, const int* __restrict__ labels,
                 float* __restrict__ rowpart, float* __restrict__ colpart,
                 float* __restrict__ Cs, float* __restrict__ cntf) {
  __shared__ unsigned char A8[32768];   // 32 KB fp8 A panel
  __shared__ unsigned char B8[32768];   // 32 KB fp8 B panel
  __shared__ float sred[4][64];
  __shared__ float cred[4][64];
  __shared__ int list[256];
  __shared__ int wscan[4];
  int tid = threadIdx.x, lane = tid & 63, wave = tid >> 6;
  int g = lane >> 4, cl = lane & 15;

  if (blockIdx.x < 100) {
    // ---------------- classsum for class c (deterministic scan) -------------
    int c = blockIdx.x;
    int base0 = tid * 32;
    int mycnt = 0;
    for (int i2 = 0; i2 < 32; ++i2) mycnt += (labels[base0 + i2] == c) ? 1 : 0;
    int inc = mycnt;
#pragma unroll
    for (int d = 1; d < 64; d <<= 1) {
      int v2 = __shfl_up(inc, d);
      if (lane >= d) inc += v2;
    }
    if (lane == 63) wscan[wave] = inc;
    __syncthreads();
    int wbase = 0, ntot = 0;
#pragma unroll
    for (int w = 0; w < 4; ++w) {
      wbase += (w < wave) ? wscan[w] : 0;
      ntot += wscan[w];
    }
    int off = wbase + inc - mycnt;
    for (int i2 = 0; i2 < 32; ++i2) {
      int idx = base0 + i2;
      if (labels[idx] == c) list[off++] = idx;
    }
    __syncthreads();
    float a0 = 0.f;
    for (int k = 0; k < ntot; ++k)
      a0 += bf2f(hs[(size_t)list[k] * ND + tid]);
    Cs[c * ND + tid] = a0;
    if (tid == 0) cntf[c] = (float)ntot;
    return;
  }

  // ---------------- 128x128 triangle tile, single-shot LDS staging ----------
  int tix = blockIdx.x - 100;
  int nid = (tix & 7) * 260 + (tix >> 3);   // bijective (2080 = 8*260)
  int rb = 0, t2 = nid;
  while (t2 >= 64 - rb) { t2 -= 64 - rb; ++rb; }
  int cb = rb + t2;
  bool diag = (rb == cb);
  int wr = (wave >> 1) * 64, wc = (wave & 1) * 64;

  stage32k(A8, hsK8 + (size_t)rb * 32768, tid);
  if (!diag) stage32k(B8, hsK8 + (size_t)cb * 32768, tid);
  __syncthreads();                        // single barrier: panels resident
  const unsigned char* At = A8;
  const unsigned char* Bt = diag ? A8 : B8;

  f32x4 acc[4][4];
#pragma unroll
  for (int rf = 0; rf < 4; ++rf)
#pragma unroll
    for (int cf = 0; cf < 4; ++cf) acc[rf][cf] = (f32x4){0.f, 0.f, 0.f, 0.f};

#pragma unroll
  for (int kk = 0; kk < 8; ++kk) {
    int ku = kk * 4 + g;
    long bfr[4];
#pragma unroll
    for (int cf = 0; cf < 4; ++cf)
      bfr[cf] = *reinterpret_cast<const long*>(
          Bt + (size_t)(ku * 128 + wc + cf * 16 + cl) * 8);
#pragma unroll
    for (int rf = 0; rf < 4; ++rf) {
      long a = *reinterpret_cast<const long*>(
          At + (size_t)(ku * 128 + wr + rf * 16 + cl) * 8);
#pragma unroll
      for (int cf = 0; cf < 4; ++cf)
        acc[rf][cf] = __builtin_amdgcn_mfma_f32_16x16x32_fp8_fp8(
            a, bfr[cf], acc[rf][cf], 0, 0, 0);
    }
  }

  // epilogue: exp2 -> per-wave row sums (over cf,cl) and col sums (rf,q,g)
  float sr[16], cc[4];
#pragma unroll
  for (int i = 0; i < 16; ++i) sr[i] = 0.f;
#pragma unroll
  for (int i = 0; i < 4; ++i) cc[i] = 0.f;
#pragma unroll
  for (int rf = 0; rf < 4; ++rf)
#pragma unroll
    for (int cf = 0; cf < 4; ++cf)
#pragma unroll
      for (int q = 0; q < 4; ++q) {
        float e = __builtin_amdgcn_exp2f(acc[rf][cf][q]);
        sr[rf * 4 + q] += e;
        cc[cf] += e;
      }
#pragma unroll
  for (int i = 0; i < 16; ++i) {
#pragma unroll
    for (int d = 1; d <= 8; d <<= 1) sr[i] += __shfl_xor(sr[i], d);
  }
#pragma unroll
  for (int i = 0; i < 4; ++i) {
    cc[i] += __shfl_xor(cc[i], 16);
    cc[i] += __shfl_xor(cc[i], 32);
  }
  if (cl == 0) {
#pragma unroll
    for (int rf = 0; rf < 4; ++rf)
#pragma unroll
      for (int q = 0; q < 4; ++q)
        sred[wave][rf * 16 + g * 4 + q] = sr[rf * 4 + q];
  }
  if (g == 0) {
#pragma unroll
    for (int cf = 0; cf < 4; ++cf) cred[wave][cf * 16 + cl] = cc[cf];
  }
  __syncthreads();
  if (tid < 128) {
    int half = tid >> 6, idx = tid & 63;
    float rv = sred[half * 2 + 0][idx] + sred[half * 2 + 1][idx];
    rowpart[(size_t)cb * NB + rb * 128 + half * 64 + idx] = rv;
    if (!diag) {
      float cv2 = cred[half][idx] + cred[half + 2][idx];
      colpart[(size_t)rb * NB + cb * 128 + half * 64 + idx] = cv2;
    }
  }
}

// ---- per-row loss ----------------------------------------------------------
__global__ void rowloss_kernel(const ushort* __restrict__ hs,
                               const int* __restrict__ labels,
                               const float* __restrict__ Cs,
                               const float* __restrict__ cntf,
                               const float* __restrict__ rowpart,
                               const float* __restrict__ colpart,
                               const float* __restrict__ dbuf,
                               float2* __restrict__ rl) {
  int lane = threadIdx.x & 63, wave = threadIdx.x >> 6;
  int row = blockIdx.x * 4 + wave;
  int lbl = labels[row];
  ushort4 qb = reinterpret_cast<const ushort4*>(hs + (size_t)row * ND)[lane];
  float4 cv = reinterpret_cast<const float4*>(Cs + (size_t)lbl * ND)[lane];
  float dot = bf2f(qb.x) * cv.x + bf2f(qb.y) * cv.y +
              bf2f(qb.z) * cv.z + bf2f(qb.w) * cv.w;
#pragma unroll
  for (int d = 1; d <= 32; d <<= 1) dot += __shfl_xor(dot, d);

  int rb0 = row >> 7;   // this row's 128-tile index (0..63)
  const float* basep = (lane >= rb0) ? rowpart : colpart;
  float part = basep[(size_t)lane * NB + row];
#pragma unroll
  for (int d = 1; d <= 32; d <<= 1) part += __shfl_xor(part, d);

  if (lane == 0) {
    float dself = dbuf[row];
    float s = part - (1.0f - 1e-8f) * __builtin_amdgcn_exp2f(dself);
    float denom2 = log2f(s);
    float Sp2 = dot - dself;
    float n = cntf[lbl] - 1.0f;
    float li = 0.f, val = 0.f;
    if (n > 0.5f) { li = -LN2f * (Sp2 - n * denom2) / n; val = 1.f; }
    rl[row] = make_float2(li, val);
  }
}

__global__ __launch_bounds__(1024)
void reduce_kernel(const float2* __restrict__ rl, float* __restrict__ out) {
  int t = threadIdx.x;
  float L = 0.f, V = 0.f;
  for (int r = t; r < NB; r += 1024) { float2 p = rl[r]; L += p.x; V += p.y; }
#pragma unroll
  for (int d = 1; d <= 32; d <<= 1) { L += __shfl_xor(L, d); V += __shfl_xor(V, d); }
  __shared__ float sL[16], sV[16];
  if ((t & 63) == 0) { sL[t >> 6] = L; sV[t >> 6] = V; }
  __syncthreads();
  if (t == 0) {
    float Ls = 0.f, Vs = 0.f;
#pragma unroll
    for (int i = 0; i < 16; ++i) { Ls += sL[i]; Vs += sV[i]; }
    out[0] = Ls / fmaxf(Vs, 1.f);
  }
}

extern "C" void kernel_launch(void* const* d_in, const int* in_sizes, int n_in,
                              void* d_out, int out_size, void* d_ws, size_t ws_size,
                              hipStream_t stream) {
  const float* hidden = (const float*)d_in[0];
  const int* labels = (const int*)d_in[1];
  float* out = (float*)d_out;
  char* w = (char*)d_ws;
  ushort* hs        = (ushort*)(w);                  // 4 MB
  unsigned char* hsK8 = (unsigned char*)(w + 4194304);  // 2 MB
  float* dbuf       = (float*)(w + 6291456);         // 32 KB
  float* Cs         = (float*)(w + 6324224);         // 100 KB
  float* cntf       = (float*)(w + 6426624);         // 512 B
  float* rowpart    = (float*)(w + 6427136);         // 2 MB (64 x 8192)
  float* colpart    = (float*)(w + 8524288);         // 2 MB (64 x 8192)
  float2* rl        = (float2*)(w + 10621440);       // 64 KB

  prep_kernel<<<NB / 4, 256, 0, stream>>>(hidden, hs, hsK8, dbuf);
  main_kernel<<<NBT + 100, 256, 0, stream>>>(hsK8, hs, labels, rowpart, colpart,
                                             Cs, cntf);
  rowloss_kernel<<<NB / 4, 256, 0, stream>>>(hs, labels, Cs, cntf, rowpart,
                                             colpart, dbuf, rl);
  reduce_kernel<<<1, 1024, 0, stream>>>(rl, out);
}

// Round 22
// 46.290 us; speedup vs baseline: 1.0780x; 1.0780x over previous
//
#include <hip/hip_runtime.h>
#include <hip/hip_bf16.h>
#include <hip/hip_fp8.h>
#include <math.h>

typedef __attribute__((ext_vector_type(4))) float f32x4;
typedef __attribute__((ext_vector_type(8))) int v8i;

#define NB 8192
#define ND 256
#define NBT 2080          // 64*65/2 triangle tiles at 128x128
#define LN2f 0.6931471805599453f
#define SCALE1 0x7F7F7F7F  // e8m0 = 127 -> 2^0 = 1.0 in all 4 bytes

__device__ __forceinline__ float bf2f(ushort u) {
  unsigned int x = ((unsigned int)u) << 16;
  return __builtin_bit_cast(float, x);
}
__device__ __forceinline__ ushort f2bf(float x) {
  return __builtin_bit_cast(ushort, __float2bfloat16(x));
}

// ---- prep: normalize, fold 1/sqrt(T*ln2), quantize to fp8 e4m3;          ----
// ---- write hs (bf16 of dequant, exact) + hsK8 (fp8 K-major) + dbuf      ----
// hsK8 layout: [tile128][ku 0..31][row 0..127] of 8B units (ku: k-bytes ku*8..+8)
__global__ void prep_kernel(const float* __restrict__ h, ushort* __restrict__ hs,
                            unsigned char* __restrict__ hsK8,
                            float* __restrict__ dbuf) {
  const float SCALE = 1.0f / sqrtf(0.07f * LN2f);
  int lane = threadIdx.x & 63, wave = threadIdx.x >> 6;
  int r = blockIdx.x * 4 + wave;
  float4 v = reinterpret_cast<const float4*>(h + (size_t)r * ND)[lane];
  float ss = v.x * v.x + v.y * v.y + v.z * v.z + v.w * v.w;
#pragma unroll
  for (int d = 1; d <= 32; d <<= 1) ss += __shfl_xor(ss, d);
  float scale = SCALE / fmaxf(sqrtf(ss), 1e-12f);
  __hip_fp8_e4m3 q0(v.x * scale), q1(v.y * scale), q2(v.z * scale), q3(v.w * scale);
  uchar4 qb;
  qb.x = q0.__x; qb.y = q1.__x; qb.z = q2.__x; qb.w = q3.__x;
  float qx = (float)q0, qy = (float)q1, qz = (float)q2, qw = (float)q3;
  ushort4 o;
  o.x = f2bf(qx); o.y = f2bf(qy); o.z = f2bf(qz); o.w = f2bf(qw);  // exact
  reinterpret_cast<ushort4*>(hs + (size_t)r * ND)[lane] = o;
  *reinterpret_cast<uchar4*>(hsK8 + (size_t)(r >> 7) * 32768 +
                             (size_t)(lane >> 1) * 1024 + (size_t)(r & 127) * 8 +
                             (lane & 1) * 4) = qb;
  float dd = qx * qx + qy * qy + qz * qz + qw * qw;
#pragma unroll
  for (int d = 1; d <= 32; d <<= 1) dd += __shfl_xor(dd, d);
  if (lane == 0) dbuf[r] = dd;
}

// gather one 32-byte MX fragment: row, k in [ks*128 + g*32, +32)
__device__ __forceinline__ v8i loadfrag(const unsigned char* base, int ks, int g,
                                        int row) {
  v8i x;
#pragma unroll
  for (int u = 0; u < 4; ++u) {
    int ku = ks * 16 + g * 4 + u;
    int2 p = *reinterpret_cast<const int2*>(base + (size_t)(ku * 128 + row) * 8);
    x[u * 2] = p.x;
    x[u * 2 + 1] = p.y;
  }
  return x;
}

// ---- main: 100 classsum blocks first, then 2080 MX-fp8 triangle tiles ------
__global__ __launch_bounds__(256)
void main_kernel(const unsigned char* __restrict__ hsK8,
                 const ushort* __restrict__ hs, const int* __restrict__ labels,
                 float* __restrict__ rowpart, float* __restrict__ colpart,
                 float* __restrict__ Cs, float* __restrict__ cntf) {
  __shared__ float sred[4][64];
  __shared__ float cred[4][64];
  __shared__ int list[256];
  __shared__ int wscan[4];
  int tid = threadIdx.x, lane = tid & 63, wave = tid >> 6;
  int g = lane >> 4, cl = lane & 15;

  if (blockIdx.x < 100) {
    // ---------------- classsum for class c (deterministic scan) -------------
    int c = blockIdx.x;
    int base0 = tid * 32;
    int mycnt = 0;
    for (int i2 = 0; i2 < 32; ++i2) mycnt += (labels[base0 + i2] == c) ? 1 : 0;
    int inc = mycnt;
#pragma unroll
    for (int d = 1; d < 64; d <<= 1) {
      int v2 = __shfl_up(inc, d);
      if (lane >= d) inc += v2;
    }
    if (lane == 63) wscan[wave] = inc;
    __syncthreads();
    int wbase = 0, ntot = 0;
#pragma unroll
    for (int w = 0; w < 4; ++w) {
      wbase += (w < wave) ? wscan[w] : 0;
      ntot += wscan[w];
    }
    int off = wbase + inc - mycnt;
    for (int i2 = 0; i2 < 32; ++i2) {
      int idx = base0 + i2;
      if (labels[idx] == c) list[off++] = idx;
    }
    __syncthreads();
    float a0 = 0.f;
    for (int k = 0; k < ntot; ++k)
      a0 += bf2f(hs[(size_t)list[k] * ND + tid]);
    Cs[c * ND + tid] = a0;
    if (tid == 0) cntf[c] = (float)ntot;
    return;
  }

  // ---------------- 128x128 triangle tile, MX K=128 direct-L2 ---------------
  int tix = blockIdx.x - 100;
  int nid = (tix & 7) * 260 + (tix >> 3);   // bijective (2080 = 8*260)
  int rb = 0, t2 = nid;
  while (t2 >= 64 - rb) { t2 -= 64 - rb; ++rb; }
  int cb = rb + t2;
  bool diag = (rb == cb);
  int wr = (wave >> 1) * 64, wc = (wave & 1) * 64;

  const unsigned char* Abase = hsK8 + (size_t)rb * 32768;
  const unsigned char* Bbase = hsK8 + (size_t)cb * 32768;

  f32x4 acc[4][4];
#pragma unroll
  for (int rf = 0; rf < 4; ++rf)
#pragma unroll
    for (int cf = 0; cf < 4; ++cf) acc[rf][cf] = (f32x4){0.f, 0.f, 0.f, 0.f};

#pragma unroll
  for (int ks = 0; ks < 2; ++ks) {
    v8i bfr[4];
#pragma unroll
    for (int cf = 0; cf < 4; ++cf)
      bfr[cf] = loadfrag(Bbase, ks, g, wc + cf * 16 + cl);
#pragma unroll
    for (int rf = 0; rf < 4; ++rf) {
      v8i a = loadfrag(Abase, ks, g, wr + rf * 16 + cl);
#pragma unroll
      for (int cf = 0; cf < 4; ++cf)
        acc[rf][cf] = __builtin_amdgcn_mfma_scale_f32_16x16x128_f8f6f4(
            a, bfr[cf], acc[rf][cf], 0, 0, 0, SCALE1, 0, SCALE1);
    }
  }

  // epilogue: exp2 -> per-wave row sums (over cf,cl) and col sums (rf,q,g)
  float sr[16], cc[4];
#pragma unroll
  for (int i = 0; i < 16; ++i) sr[i] = 0.f;
#pragma unroll
  for (int i = 0; i < 4; ++i) cc[i] = 0.f;
#pragma unroll
  for (int rf = 0; rf < 4; ++rf)
#pragma unroll
    for (int cf = 0; cf < 4; ++cf)
#pragma unroll
      for (int q = 0; q < 4; ++q) {
        float e = __builtin_amdgcn_exp2f(acc[rf][cf][q]);
        sr[rf * 4 + q] += e;
        cc[cf] += e;
      }
#pragma unroll
  for (int i = 0; i < 16; ++i) {
#pragma unroll
    for (int d = 1; d <= 8; d <<= 1) sr[i] += __shfl_xor(sr[i], d);
  }
#pragma unroll
  for (int i = 0; i < 4; ++i) {
    cc[i] += __shfl_xor(cc[i], 16);
    cc[i] += __shfl_xor(cc[i], 32);
  }
  if (cl == 0) {
#pragma unroll
    for (int rf = 0; rf < 4; ++rf)
#pragma unroll
      for (int q = 0; q < 4; ++q)
        sred[wave][rf * 16 + g * 4 + q] = sr[rf * 4 + q];
  }
  if (g == 0) {
#pragma unroll
    for (int cf = 0; cf < 4; ++cf) cred[wave][cf * 16 + cl] = cc[cf];
  }
  __syncthreads();
  if (tid < 128) {
    int half = tid >> 6, idx = tid & 63;
    float rv = sred[half * 2 + 0][idx] + sred[half * 2 + 1][idx];
    rowpart[(size_t)cb * NB + rb * 128 + half * 64 + idx] = rv;
    if (!diag) {
      float cv2 = cred[half][idx] + cred[half + 2][idx];
      colpart[(size_t)rb * NB + cb * 128 + half * 64 + idx] = cv2;
    }
  }
}

// ---- per-row loss ----------------------------------------------------------
__global__ void rowloss_kernel(const ushort* __restrict__ hs,
                               const int* __restrict__ labels,
                               const float* __restrict__ Cs,
                               const float* __restrict__ cntf,
                               const float* __restrict__ rowpart,
                               const float* __restrict__ colpart,
                               const float* __restrict__ dbuf,
                               float2* __restrict__ rl) {
  int lane = threadIdx.x & 63, wave = threadIdx.x >> 6;
  int row = blockIdx.x * 4 + wave;
  int lbl = labels[row];
  ushort4 qb = reinterpret_cast<const ushort4*>(hs + (size_t)row * ND)[lane];
  float4 cv = reinterpret_cast<const float4*>(Cs + (size_t)lbl * ND)[lane];
  float dot = bf2f(qb.x) * cv.x + bf2f(qb.y) * cv.y +
              bf2f(qb.z) * cv.z + bf2f(qb.w) * cv.w;
#pragma unroll
  for (int d = 1; d <= 32; d <<= 1) dot += __shfl_xor(dot, d);

  int rb0 = row >> 7;   // this row's 128-tile index (0..63)
  const float* basep = (lane >= rb0) ? rowpart : colpart;
  float part = basep[(size_t)lane * NB + row];
#pragma unroll
  for (int d = 1; d <= 32; d <<= 1) part += __shfl_xor(part, d);

  if (lane == 0) {
    float dself = dbuf[row];
    float s = part - (1.0f - 1e-8f) * __builtin_amdgcn_exp2f(dself);
    float denom2 = log2f(s);
    float Sp2 = dot - dself;
    float n = cntf[lbl] - 1.0f;
    float li = 0.f, val = 0.f;
    if (n > 0.5f) { li = -LN2f * (Sp2 - n * denom2) / n; val = 1.f; }
    rl[row] = make_float2(li, val);
  }
}

__global__ __launch_bounds__(1024)
void reduce_kernel(const float2* __restrict__ rl, float* __restrict__ out) {
  int t = threadIdx.x;
  float L = 0.f, V = 0.f;
  for (int r = t; r < NB; r += 1024) { float2 p = rl[r]; L += p.x; V += p.y; }
#pragma unroll
  for (int d = 1; d <= 32; d <<= 1) { L += __shfl_xor(L, d); V += __shfl_xor(V, d); }
  __shared__ float sL[16], sV[16];
  if ((t & 63) == 0) { sL[t >> 6] = L; sV[t >> 6] = V; }
  __syncthreads();
  if (t == 0) {
    float Ls = 0.f, Vs = 0.f;
#pragma unroll
    for (int i = 0; i < 16; ++i) { Ls += sL[i]; Vs += sV[i]; }
    out[0] = Ls / fmaxf(Vs, 1.f);
  }
}

extern "C" void kernel_launch(void* const* d_in, const int* in_sizes, int n_in,
                              void* d_out, int out_size, void* d_ws, size_t ws_size,
                              hipStream_t stream) {
  const float* hidden = (const float*)d_in[0];
  const int* labels = (const int*)d_in[1];
  float* out = (float*)d_out;
  char* w = (char*)d_ws;
  ushort* hs        = (ushort*)(w);                  // 4 MB
  unsigned char* hsK8 = (unsigned char*)(w + 4194304);  // 2 MB
  float* dbuf       = (float*)(w + 6291456);         // 32 KB
  float* Cs         = (float*)(w + 6324224);         // 100 KB
  float* cntf       = (float*)(w + 6426624);         // 512 B
  float* rowpart    = (float*)(w + 6427136);         // 2 MB (64 x 8192)
  float* colpart    = (float*)(w + 8524288);         // 2 MB (64 x 8192)
  float2* rl        = (float2*)(w + 10621440);       // 64 KB

  prep_kernel<<<NB / 4, 256, 0, stream>>>(hidden, hs, hsK8, dbuf);
  main_kernel<<<NBT + 100, 256, 0, stream>>>(hsK8, hs, labels, rowpart, colpart,
                                             Cs, cntf);
  rowloss_kernel<<<NB / 4, 256, 0, stream>>>(hs, labels, Cs, cntf, rowpart,
                                             colpart, dbuf, rl);
  reduce_kernel<<<1, 1024, 0, stream>>>(rl, out);
}

// Round 23
// 45.697 us; speedup vs baseline: 1.0920x; 1.0130x over previous
//
#include <hip/hip_runtime.h>
#include <hip/hip_bf16.h>
#include <hip/hip_fp8.h>
#include <math.h>

typedef __attribute__((ext_vector_type(4))) float f32x4;
typedef __attribute__((ext_vector_type(8))) int v8i;

#define NB 8192
#define ND 256
#define NBT 2080          // 64*65/2 triangle tiles at 128x128
#define LN2f 0.6931471805599453f
#define SCALE1 0x7F7F7F7F  // e8m0 = 127 -> 2^0 = 1.0 in all 4 bytes

__device__ __forceinline__ float bf2f(ushort u) {
  unsigned int x = ((unsigned int)u) << 16;
  return __builtin_bit_cast(float, x);
}
__device__ __forceinline__ ushort f2bf(float x) {
  return __builtin_bit_cast(ushort, __float2bfloat16(x));
}

// ---- prep: normalize, fold 1/sqrt(T*ln2), quantize to fp8 e4m3;          ----
// ---- write hs (bf16 of dequant, exact) + hsKX (MX-native frags) + dbuf  ----
// hsKX layout: [tile128][ks 0..1][g 0..3][row 0..127][32B]  (lane fragment
// = k-bytes [ks*128+g*32, +32) of its row, stored contiguously)
__global__ void prep_kernel(const float* __restrict__ h, ushort* __restrict__ hs,
                            unsigned char* __restrict__ hsKX,
                            float* __restrict__ dbuf) {
  const float SCALE = 1.0f / sqrtf(0.07f * LN2f);
  int lane = threadIdx.x & 63, wave = threadIdx.x >> 6;
  int r = blockIdx.x * 4 + wave;
  float4 v = reinterpret_cast<const float4*>(h + (size_t)r * ND)[lane];
  float ss = v.x * v.x + v.y * v.y + v.z * v.z + v.w * v.w;
#pragma unroll
  for (int d = 1; d <= 32; d <<= 1) ss += __shfl_xor(ss, d);
  float scale = SCALE / fmaxf(sqrtf(ss), 1e-12f);
  __hip_fp8_e4m3 q0(v.x * scale), q1(v.y * scale), q2(v.z * scale), q3(v.w * scale);
  uchar4 qb;
  qb.x = q0.__x; qb.y = q1.__x; qb.z = q2.__x; qb.w = q3.__x;
  float qx = (float)q0, qy = (float)q1, qz = (float)q2, qw = (float)q3;
  ushort4 o;
  o.x = f2bf(qx); o.y = f2bf(qy); o.z = f2bf(qz); o.w = f2bf(qw);  // exact
  reinterpret_cast<ushort4*>(hs + (size_t)r * ND)[lane] = o;
  // lane holds k-bytes [4*lane, 4*lane+4): chunk c = lane>>3 -> ks=c>>2, g=c&3
  int c = lane >> 3;
  *reinterpret_cast<uchar4*>(hsKX + (size_t)(r >> 7) * 32768 + (c >> 2) * 16384 +
                             (c & 3) * 4096 + (size_t)(r & 127) * 32 +
                             (lane & 7) * 4) = qb;
  float dd = qx * qx + qy * qy + qz * qz + qw * qw;
#pragma unroll
  for (int d = 1; d <= 32; d <<= 1) dd += __shfl_xor(dd, d);
  if (lane == 0) dbuf[r] = dd;
}

// one MX fragment = 32 contiguous bytes = 2 x 16B loads
__device__ __forceinline__ v8i loadfrag(const unsigned char* base, int ks, int g,
                                        int row) {
  const int4* p = reinterpret_cast<const int4*>(base + ks * 16384 + g * 4096 +
                                                (size_t)row * 32);
  int4 lo = p[0], hi = p[1];
  v8i x;
  x[0] = lo.x; x[1] = lo.y; x[2] = lo.z; x[3] = lo.w;
  x[4] = hi.x; x[5] = hi.y; x[6] = hi.z; x[7] = hi.w;
  return x;
}

// ---- main: 100 classsum blocks first, then 2080 MX-fp8 triangle tiles ------
__global__ __launch_bounds__(256)
void main_kernel(const unsigned char* __restrict__ hsKX,
                 const ushort* __restrict__ hs, const int* __restrict__ labels,
                 float* __restrict__ rowpart, float* __restrict__ colpart,
                 float* __restrict__ Cs, float* __restrict__ cntf) {
  __shared__ float sred[4][64];
  __shared__ float cred[4][64];
  __shared__ int list[256];
  __shared__ int wscan[4];
  int tid = threadIdx.x, lane = tid & 63, wave = tid >> 6;
  int g = lane >> 4, cl = lane & 15;

  if (blockIdx.x < 100) {
    // ---------------- classsum for class c (deterministic scan) -------------
    int c = blockIdx.x;
    int base0 = tid * 32;
    int mycnt = 0;
    for (int i2 = 0; i2 < 32; ++i2) mycnt += (labels[base0 + i2] == c) ? 1 : 0;
    int inc = mycnt;
#pragma unroll
    for (int d = 1; d < 64; d <<= 1) {
      int v2 = __shfl_up(inc, d);
      if (lane >= d) inc += v2;
    }
    if (lane == 63) wscan[wave] = inc;
    __syncthreads();
    int wbase = 0, ntot = 0;
#pragma unroll
    for (int w = 0; w < 4; ++w) {
      wbase += (w < wave) ? wscan[w] : 0;
      ntot += wscan[w];
    }
    int off = wbase + inc - mycnt;
    for (int i2 = 0; i2 < 32; ++i2) {
      int idx = base0 + i2;
      if (labels[idx] == c) list[off++] = idx;
    }
    __syncthreads();
    float a0 = 0.f;
    for (int k = 0; k < ntot; ++k)
      a0 += bf2f(hs[(size_t)list[k] * ND + tid]);
    Cs[c * ND + tid] = a0;
    if (tid == 0) cntf[c] = (float)ntot;
    return;
  }

  // ---------------- 128x128 triangle tile, MX K=128, 16B direct-L2 ----------
  int tix = blockIdx.x - 100;
  int nid = (tix & 7) * 260 + (tix >> 3);   // bijective (2080 = 8*260)
  int rb = 0, t2 = nid;
  while (t2 >= 64 - rb) { t2 -= 64 - rb; ++rb; }
  int cb = rb + t2;
  bool diag = (rb == cb);
  int wr = (wave >> 1) * 64, wc = (wave & 1) * 64;

  const unsigned char* Abase = hsKX + (size_t)rb * 32768;
  const unsigned char* Bbase = hsKX + (size_t)cb * 32768;

  f32x4 acc[4][4];
#pragma unroll
  for (int rf = 0; rf < 4; ++rf)
#pragma unroll
    for (int cf = 0; cf < 4; ++cf) acc[rf][cf] = (f32x4){0.f, 0.f, 0.f, 0.f};

#pragma unroll
  for (int ks = 0; ks < 2; ++ks) {
    v8i bfr[4];
#pragma unroll
    for (int cf = 0; cf < 4; ++cf)
      bfr[cf] = loadfrag(Bbase, ks, g, wc + cf * 16 + cl);
#pragma unroll
    for (int rf = 0; rf < 4; ++rf) {
      v8i a = loadfrag(Abase, ks, g, wr + rf * 16 + cl);
#pragma unroll
      for (int cf = 0; cf < 4; ++cf)
        acc[rf][cf] = __builtin_amdgcn_mfma_scale_f32_16x16x128_f8f6f4(
            a, bfr[cf], acc[rf][cf], 0, 0, 0, SCALE1, 0, SCALE1);
    }
  }

  // epilogue: exp2 -> per-wave row sums (over cf,cl) and col sums (rf,q,g)
  float sr[16], cc[4];
#pragma unroll
  for (int i = 0; i < 16; ++i) sr[i] = 0.f;
#pragma unroll
  for (int i = 0; i < 4; ++i) cc[i] = 0.f;
#pragma unroll
  for (int rf = 0; rf < 4; ++rf)
#pragma unroll
    for (int cf = 0; cf < 4; ++cf)
#pragma unroll
      for (int q = 0; q < 4; ++q) {
        float e = __builtin_amdgcn_exp2f(acc[rf][cf][q]);
        sr[rf * 4 + q] += e;
        cc[cf] += e;
      }
#pragma unroll
  for (int i = 0; i < 16; ++i) {
#pragma unroll
    for (int d = 1; d <= 8; d <<= 1) sr[i] += __shfl_xor(sr[i], d);
  }
#pragma unroll
  for (int i = 0; i < 4; ++i) {
    cc[i] += __shfl_xor(cc[i], 16);
    cc[i] += __shfl_xor(cc[i], 32);
  }
  if (cl == 0) {
#pragma unroll
    for (int rf = 0; rf < 4; ++rf)
#pragma unroll
      for (int q = 0; q < 4; ++q)
        sred[wave][rf * 16 + g * 4 + q] = sr[rf * 4 + q];
  }
  if (g == 0) {
#pragma unroll
    for (int cf = 0; cf < 4; ++cf) cred[wave][cf * 16 + cl] = cc[cf];
  }
  __syncthreads();
  if (tid < 128) {
    int half = tid >> 6, idx = tid & 63;
    float rv = sred[half * 2 + 0][idx] + sred[half * 2 + 1][idx];
    rowpart[(size_t)cb * NB + rb * 128 + half * 64 + idx] = rv;
    if (!diag) {
      float cv2 = cred[half][idx] + cred[half + 2][idx];
      colpart[(size_t)rb * NB + cb * 128 + half * 64 + idx] = cv2;
    }
  }
}

// ---- per-row loss ----------------------------------------------------------
__global__ void rowloss_kernel(const ushort* __restrict__ hs,
                               const int* __restrict__ labels,
                               const float* __restrict__ Cs,
                               const float* __restrict__ cntf,
                               const float* __restrict__ rowpart,
                               const float* __restrict__ colpart,
                               const float* __restrict__ dbuf,
                               float2* __restrict__ rl) {
  int lane = threadIdx.x & 63, wave = threadIdx.x >> 6;
  int row = blockIdx.x * 4 + wave;
  int lbl = labels[row];
  ushort4 qb = reinterpret_cast<const ushort4*>(hs + (size_t)row * ND)[lane];
  float4 cv = reinterpret_cast<const float4*>(Cs + (size_t)lbl * ND)[lane];
  float dot = bf2f(qb.x) * cv.x + bf2f(qb.y) * cv.y +
              bf2f(qb.z) * cv.z + bf2f(qb.w) * cv.w;
#pragma unroll
  for (int d = 1; d <= 32; d <<= 1) dot += __shfl_xor(dot, d);

  int rb0 = row >> 7;   // this row's 128-tile index (0..63)
  const float* basep = (lane >= rb0) ? rowpart : colpart;
  float part = basep[(size_t)lane * NB + row];
#pragma unroll
  for (int d = 1; d <= 32; d <<= 1) part += __shfl_xor(part, d);

  if (lane == 0) {
    float dself = dbuf[row];
    float s = part - (1.0f - 1e-8f) * __builtin_amdgcn_exp2f(dself);
    float denom2 = log2f(s);
    float Sp2 = dot - dself;
    float n = cntf[lbl] - 1.0f;
    float li = 0.f, val = 0.f;
    if (n > 0.5f) { li = -LN2f * (Sp2 - n * denom2) / n; val = 1.f; }
    rl[row] = make_float2(li, val);
  }
}

__global__ __launch_bounds__(1024)
void reduce_kernel(const float2* __restrict__ rl, float* __restrict__ out) {
  int t = threadIdx.x;
  float L = 0.f, V = 0.f;
  for (int r = t; r < NB; r += 1024) { float2 p = rl[r]; L += p.x; V += p.y; }
#pragma unroll
  for (int d = 1; d <= 32; d <<= 1) { L += __shfl_xor(L, d); V += __shfl_xor(V, d); }
  __shared__ float sL[16], sV[16];
  if ((t & 63) == 0) { sL[t >> 6] = L; sV[t >> 6] = V; }
  __syncthreads();
  if (t == 0) {
    float Ls = 0.f, Vs = 0.f;
#pragma unroll
    for (int i = 0; i < 16; ++i) { Ls += sL[i]; Vs += sV[i]; }
    out[0] = Ls / fmaxf(Vs, 1.f);
  }
}

extern "C" void kernel_launch(void* const* d_in, const int* in_sizes, int n_in,
                              void* d_out, int out_size, void* d_ws, size_t ws_size,
                              hipStream_t stream) {
  const float* hidden = (const float*)d_in[0];
  const int* labels = (const int*)d_in[1];
  float* out = (float*)d_out;
  char* w = (char*)d_ws;
  ushort* hs        = (ushort*)(w);                  // 4 MB
  unsigned char* hsKX = (unsigned char*)(w + 4194304);  // 2 MB
  float* dbuf       = (float*)(w + 6291456);         // 32 KB
  float* Cs         = (float*)(w + 6324224);         // 100 KB
  float* cntf       = (float*)(w + 6426624);         // 512 B
  float* rowpart    = (float*)(w + 6427136);         // 2 MB (64 x 8192)
  float* colpart    = (float*)(w + 8524288);         // 2 MB (64 x 8192)
  float2* rl        = (float2*)(w + 10621440);       // 64 KB

  prep_kernel<<<NB / 4, 256, 0, stream>>>(hidden, hs, hsKX, dbuf);
  main_kernel<<<NBT + 100, 256, 0, stream>>>(hsKX, hs, labels, rowpart, colpart,
                                             Cs, cntf);
  rowloss_kernel<<<NB / 4, 256, 0, stream>>>(hs, labels, Cs, cntf, rowpart,
                                             colpart, dbuf, rl);
  reduce_kernel<<<1, 1024, 0, stream>>>(rl, out);
}

// Round 24
// 45.673 us; speedup vs baseline: 1.0926x; 1.0005x over previous
//
#include <hip/hip_runtime.h>
#include <hip/hip_bf16.h>
#include <hip/hip_fp8.h>
#include <math.h>

typedef __attribute__((ext_vector_type(4))) float f32x4;
typedef __attribute__((ext_vector_type(8))) int v8i;

#define NB 8192
#define ND 256
#define NBT 2080          // 64*65/2 triangle tiles at 128x128
#define LN2f 0.6931471805599453f
#define SCALE1 0x7F7F7F7F  // e8m0 = 127 -> 2^0 = 1.0 in all 4 bytes

__device__ __forceinline__ float bf2f(ushort u) {
  unsigned int x = ((unsigned int)u) << 16;
  return __builtin_bit_cast(float, x);
}
__device__ __forceinline__ ushort f2bf(float x) {
  return __builtin_bit_cast(ushort, __float2bfloat16(x));
}

// ---- prep: normalize, fold 1/sqrt(T*ln2), quantize to fp8 e4m3;          ----
// ---- write hs (bf16 of dequant, exact) + hsKX (MX-native frags) + dbuf  ----
// hsKX layout: [tile128][ks 0..1][g 0..3][row 0..127][32B]
__global__ void prep_kernel(const float* __restrict__ h, ushort* __restrict__ hs,
                            unsigned char* __restrict__ hsKX,
                            float* __restrict__ dbuf) {
  const float SCALE = 1.0f / sqrtf(0.07f * LN2f);
  int lane = threadIdx.x & 63, wave = threadIdx.x >> 6;
  int r = blockIdx.x * 4 + wave;
  float4 v = reinterpret_cast<const float4*>(h + (size_t)r * ND)[lane];
  float ss = v.x * v.x + v.y * v.y + v.z * v.z + v.w * v.w;
#pragma unroll
  for (int d = 1; d <= 32; d <<= 1) ss += __shfl_xor(ss, d);
  float scale = SCALE / fmaxf(sqrtf(ss), 1e-12f);
  __hip_fp8_e4m3 q0(v.x * scale), q1(v.y * scale), q2(v.z * scale), q3(v.w * scale);
  uchar4 qb;
  qb.x = q0.__x; qb.y = q1.__x; qb.z = q2.__x; qb.w = q3.__x;
  float qx = (float)q0, qy = (float)q1, qz = (float)q2, qw = (float)q3;
  ushort4 o;
  o.x = f2bf(qx); o.y = f2bf(qy); o.z = f2bf(qz); o.w = f2bf(qw);  // exact
  reinterpret_cast<ushort4*>(hs + (size_t)r * ND)[lane] = o;
  int c = lane >> 3;
  *reinterpret_cast<uchar4*>(hsKX + (size_t)(r >> 7) * 32768 + (c >> 2) * 16384 +
                             (c & 3) * 4096 + (size_t)(r & 127) * 32 +
                             (lane & 7) * 4) = qb;
  float dd = qx * qx + qy * qy + qz * qz + qw * qw;
#pragma unroll
  for (int d = 1; d <= 32; d <<= 1) dd += __shfl_xor(dd, d);
  if (lane == 0) dbuf[r] = dd;
}

// one MX fragment = 32 contiguous bytes = 2 x 16B loads
__device__ __forceinline__ v8i loadfrag(const unsigned char* base, int ks, int g,
                                        int row) {
  const int4* p = reinterpret_cast<const int4*>(base + ks * 16384 + g * 4096 +
                                                (size_t)row * 32);
  int4 lo = p[0], hi = p[1];
  v8i x;
  x[0] = lo.x; x[1] = lo.y; x[2] = lo.z; x[3] = lo.w;
  x[4] = hi.x; x[5] = hi.y; x[6] = hi.z; x[7] = hi.w;
  return x;
}

// ---- main: 100 classsum blocks first, then 2080 MX-fp8 triangle tiles ------
__global__ __launch_bounds__(256)
void main_kernel(const unsigned char* __restrict__ hsKX,
                 const ushort* __restrict__ hs, const int* __restrict__ labels,
                 float* __restrict__ rowpart, float* __restrict__ colpart,
                 float* __restrict__ Cs, float* __restrict__ cntf) {
  __shared__ float sred[4][64];
  __shared__ float cred[4][64];
  __shared__ int list[256];
  __shared__ int wscan[4];
  int tid = threadIdx.x, lane = tid & 63, wave = tid >> 6;
  int g = lane >> 4, cl = lane & 15;

  if (blockIdx.x < 100) {
    // ---------------- classsum for class c (deterministic scan) -------------
    int c = blockIdx.x;
    int base0 = tid * 32;
    int mycnt = 0;
    for (int i2 = 0; i2 < 32; ++i2) mycnt += (labels[base0 + i2] == c) ? 1 : 0;
    int inc = mycnt;
#pragma unroll
    for (int d = 1; d < 64; d <<= 1) {
      int v2 = __shfl_up(inc, d);
      if (lane >= d) inc += v2;
    }
    if (lane == 63) wscan[wave] = inc;
    __syncthreads();
    int wbase = 0, ntot = 0;
#pragma unroll
    for (int w = 0; w < 4; ++w) {
      wbase += (w < wave) ? wscan[w] : 0;
      ntot += wscan[w];
    }
    int off = wbase + inc - mycnt;
    for (int i2 = 0; i2 < 32; ++i2) {
      int idx = base0 + i2;
      if (labels[idx] == c) list[off++] = idx;
    }
    __syncthreads();
    // 8-way unrolled member sum: 8 independent loads in flight per group
    float a0 = 0.f;
    int k = 0;
    for (; k + 8 <= ntot; k += 8) {
      float t0 = bf2f(hs[(size_t)list[k + 0] * ND + tid]);
      float t1 = bf2f(hs[(size_t)list[k + 1] * ND + tid]);
      float t2 = bf2f(hs[(size_t)list[k + 2] * ND + tid]);
      float t3 = bf2f(hs[(size_t)list[k + 3] * ND + tid]);
      float t4 = bf2f(hs[(size_t)list[k + 4] * ND + tid]);
      float t5 = bf2f(hs[(size_t)list[k + 5] * ND + tid]);
      float t6 = bf2f(hs[(size_t)list[k + 6] * ND + tid]);
      float t7 = bf2f(hs[(size_t)list[k + 7] * ND + tid]);
      a0 += ((t0 + t1) + (t2 + t3)) + ((t4 + t5) + (t6 + t7));
    }
    for (; k < ntot; ++k)
      a0 += bf2f(hs[(size_t)list[k] * ND + tid]);
    Cs[c * ND + tid] = a0;
    if (tid == 0) cntf[c] = (float)ntot;
    return;
  }

  // ---------------- 128x128 triangle tile, MX K=128, 16B direct-L2 ----------
  int tix = blockIdx.x - 100;
  int nid = (tix & 7) * 260 + (tix >> 3);   // bijective (2080 = 8*260)
  int rb = 0, t2 = nid;
  while (t2 >= 64 - rb) { t2 -= 64 - rb; ++rb; }
  int cb = rb + t2;
  bool diag = (rb == cb);
  int wr = (wave >> 1) * 64, wc = (wave & 1) * 64;

  const unsigned char* Abase = hsKX + (size_t)rb * 32768;
  const unsigned char* Bbase = hsKX + (size_t)cb * 32768;

  f32x4 acc[4][4];
#pragma unroll
  for (int rf = 0; rf < 4; ++rf)
#pragma unroll
    for (int cf = 0; cf < 4; ++cf) acc[rf][cf] = (f32x4){0.f, 0.f, 0.f, 0.f};

#pragma unroll
  for (int ks = 0; ks < 2; ++ks) {
    v8i bfr[4];
#pragma unroll
    for (int cf = 0; cf < 4; ++cf)
      bfr[cf] = loadfrag(Bbase, ks, g, wc + cf * 16 + cl);
#pragma unroll
    for (int rf = 0; rf < 4; ++rf) {
      v8i a = loadfrag(Abase, ks, g, wr + rf * 16 + cl);
#pragma unroll
      for (int cf = 0; cf < 4; ++cf)
        acc[rf][cf] = __builtin_amdgcn_mfma_scale_f32_16x16x128_f8f6f4(
            a, bfr[cf], acc[rf][cf], 0, 0, 0, SCALE1, 0, SCALE1);
    }
  }

  // epilogue: exp2 -> per-wave row sums (over cf,cl) and col sums (rf,q,g)
  float sr[16], cc[4];
#pragma unroll
  for (int i = 0; i < 16; ++i) sr[i] = 0.f;
#pragma unroll
  for (int i = 0; i < 4; ++i) cc[i] = 0.f;
#pragma unroll
  for (int rf = 0; rf < 4; ++rf)
#pragma unroll
    for (int cf = 0; cf < 4; ++cf)
#pragma unroll
      for (int q = 0; q < 4; ++q) {
        float e = __builtin_amdgcn_exp2f(acc[rf][cf][q]);
        sr[rf * 4 + q] += e;
        cc[cf] += e;
      }
#pragma unroll
  for (int i = 0; i < 16; ++i) {
#pragma unroll
    for (int d = 1; d <= 8; d <<= 1) sr[i] += __shfl_xor(sr[i], d);
  }
#pragma unroll
  for (int i = 0; i < 4; ++i) {
    cc[i] += __shfl_xor(cc[i], 16);
    cc[i] += __shfl_xor(cc[i], 32);
  }
  if (cl == 0) {
#pragma unroll
    for (int rf = 0; rf < 4; ++rf)
#pragma unroll
      for (int q = 0; q < 4; ++q)
        sred[wave][rf * 16 + g * 4 + q] = sr[rf * 4 + q];
  }
  if (g == 0) {
#pragma unroll
    for (int cf = 0; cf < 4; ++cf) cred[wave][cf * 16 + cl] = cc[cf];
  }
  __syncthreads();
  if (tid < 128) {
    int half = tid >> 6, idx = tid & 63;
    float rv = sred[half * 2 + 0][idx] + sred[half * 2 + 1][idx];
    rowpart[(size_t)cb * NB + rb * 128 + half * 64 + idx] = rv;
    if (!diag) {
      float cv2 = cred[half][idx] + cred[half + 2][idx];
      colpart[(size_t)rb * NB + cb * 128 + half * 64 + idx] = cv2;
    }
  }
}

// ---- per-row loss ----------------------------------------------------------
__global__ void rowloss_kernel(const ushort* __restrict__ hs,
                               const int* __restrict__ labels,
                               const float* __restrict__ Cs,
                               const float* __restrict__ cntf,
                               const float* __restrict__ rowpart,
                               const float* __restrict__ colpart,
                               const float* __restrict__ dbuf,
                               float2* __restrict__ rl) {
  int lane = threadIdx.x & 63, wave = threadIdx.x >> 6;
  int row = blockIdx.x * 4 + wave;
  int lbl = labels[row];
  ushort4 qb = reinterpret_cast<const ushort4*>(hs + (size_t)row * ND)[lane];
  float4 cv = reinterpret_cast<const float4*>(Cs + (size_t)lbl * ND)[lane];
  float dot = bf2f(qb.x) * cv.x + bf2f(qb.y) * cv.y +
              bf2f(qb.z) * cv.z + bf2f(qb.w) * cv.w;
#pragma unroll
  for (int d = 1; d <= 32; d <<= 1) dot += __shfl_xor(dot, d);

  int rb0 = row >> 7;   // this row's 128-tile index (0..63)
  const float* basep = (lane >= rb0) ? rowpart : colpart;
  float part = basep[(size_t)lane * NB + row];
#pragma unroll
  for (int d = 1; d <= 32; d <<= 1) part += __shfl_xor(part, d);

  if (lane == 0) {
    float dself = dbuf[row];
    float s = part - (1.0f - 1e-8f) * __builtin_amdgcn_exp2f(dself);
    float denom2 = log2f(s);
    float Sp2 = dot - dself;
    float n = cntf[lbl] - 1.0f;
    float li = 0.f, val = 0.f;
    if (n > 0.5f) { li = -LN2f * (Sp2 - n * denom2) / n; val = 1.f; }
    rl[row] = make_float2(li, val);
  }
}

__global__ __launch_bounds__(1024)
void reduce_kernel(const float2* __restrict__ rl, float* __restrict__ out) {
  int t = threadIdx.x;
  float L = 0.f, V = 0.f;
  for (int r = t; r < NB; r += 1024) { float2 p = rl[r]; L += p.x; V += p.y; }
#pragma unroll
  for (int d = 1; d <= 32; d <<= 1) { L += __shfl_xor(L, d); V += __shfl_xor(V, d); }
  __shared__ float sL[16], sV[16];
  if ((t & 63) == 0) { sL[t >> 6] = L; sV[t >> 6] = V; }
  __syncthreads();
  if (t == 0) {
    float Ls = 0.f, Vs = 0.f;
#pragma unroll
    for (int i = 0; i < 16; ++i) { Ls += sL[i]; Vs += sV[i]; }
    out[0] = Ls / fmaxf(Vs, 1.f);
  }
}

extern "C" void kernel_launch(void* const* d_in, const int* in_sizes, int n_in,
                              void* d_out, int out_size, void* d_ws, size_t ws_size,
                              hipStream_t stream) {
  const float* hidden = (const float*)d_in[0];
  const int* labels = (const int*)d_in[1];
  float* out = (float*)d_out;
  char* w = (char*)d_ws;
  ushort* hs        = (ushort*)(w);                  // 4 MB
  unsigned char* hsKX = (unsigned char*)(w + 4194304);  // 2 MB
  float* dbuf       = (float*)(w + 6291456);         // 32 KB
  float* Cs         = (float*)(w + 6324224);         // 100 KB
  float* cntf       = (float*)(w + 6426624);         // 512 B
  float* rowpart    = (float*)(w + 6427136);         // 2 MB (64 x 8192)
  float* colpart    = (float*)(w + 8524288);         // 2 MB (64 x 8192)
  float2* rl        = (float2*)(w + 10621440);       // 64 KB

  prep_kernel<<<NB / 4, 256, 0, stream>>>(hidden, hs, hsKX, dbuf);
  main_kernel<<<NBT + 100, 256, 0, stream>>>(hsKX, hs, labels, rowpart, colpart,
                                             Cs, cntf);
  rowloss_kernel<<<NB / 4, 256, 0, stream>>>(hs, labels, Cs, cntf, rowpart,
                                             colpart, dbuf, rl);
  reduce_kernel<<<1, 1024, 0, stream>>>(rl, out);
}